// Round 6
// baseline (212.338 us; speedup 1.0000x reference)
//
#include <hip/hip_runtime.h>
#include <hip/hip_bf16.h>
#include <math.h>

typedef __attribute__((ext_vector_type(8))) short bf16x8;
typedef __attribute__((ext_vector_type(4))) float f32x4;

#define NQ 16384
#define NN 32
#define FI 128
#define FO 256
#define KPN 15
#define OD 42
#define INV_EXT 0.5f

#define KT2 64            // 2048 / 32
#define WFA_STRIDE 2056   // halfwords per A row: 2048 + 8 pad (4112 B, 16B-aligned)

// ws layout (bytes)
#define WS_FEATPK 0u                      // 16384*128 u32 (hi|lo<<16) = 8 MB
#define WS_BSW    (8u * 1024u * 1024u)    // 16*64*64*8 bf16 = 1 MB
#define WS_DWBH   (9u * 1024u * 1024u)    // 196,608
#define WS_DWBL   (WS_DWBH + 196608u)

static __device__ __forceinline__ unsigned short f2bf(float x) {
    union { __hip_bfloat16 h; unsigned short u; } cv;
    cv.h = __float2bfloat16(x);
    return cv.u;
}
static __device__ __forceinline__ float bf2f(unsigned short h) {
    union { unsigned int u; float f; } cv;
    cv.u = ((unsigned int)h) << 16;
    return cv.f;
}

// ------------------------- fused pre-kernel -------------------------
// blocks [0,2048): features -> featpk (hi|lo<<16)
// blocks [2048,2304): weight -> Bsw B-fragments (kf = f*16+k)
// blocks [2304,2352): dweight -> split dwB_{hi,lo} B-fragments
__global__ void pre_all(const float* __restrict__ feat, unsigned int* __restrict__ fpk,
                        const float* __restrict__ w, unsigned short* __restrict__ Bsw,
                        const float* __restrict__ dw,
                        unsigned short* __restrict__ dhi, unsigned short* __restrict__ dlo)
{
    const int b = blockIdx.x, t = threadIdx.x;
    if (b < 2048) {
        const int i = (b * 256 + t) * 4;
        float4 a = *(const float4*)&feat[i];
        unsigned short h0 = f2bf(a.x), h1 = f2bf(a.y), h2 = f2bf(a.z), h3 = f2bf(a.w);
        fpk[i + 0] = (unsigned int)h0 | ((unsigned int)f2bf(a.x - bf2f(h0)) << 16);
        fpk[i + 1] = (unsigned int)h1 | ((unsigned int)f2bf(a.y - bf2f(h1)) << 16);
        fpk[i + 2] = (unsigned int)h2 | ((unsigned int)f2bf(a.z - bf2f(h2)) << 16);
        fpk[i + 3] = (unsigned int)h3 | ((unsigned int)f2bf(a.w - bf2f(h3)) << 16);
    } else if (b < 2048 + 256) {
        const int tid = (b - 2048) * 256 + t;     // 65536 total
        const int lane = tid & 63;
        const int kt   = (tid >> 6) & 63;
        const int nt   = tid >> 12;
        const int n    = nt * 16 + (lane & 15);
        const int kbase = kt * 32 + (lane >> 4) * 8;
        unsigned int p[4];
        #pragma unroll
        for (int jj = 0; jj < 4; jj++) {
            unsigned int lo, hi;
            {
                const int kk = kbase + 2 * jj;
                const int f = kk >> 4, k = kk & 15;
                lo = (k < KPN) ? f2bf(w[(k * FI + f) * FO + n]) : 0u;
            }
            {
                const int kk = kbase + 2 * jj + 1;
                const int f = kk >> 4, k = kk & 15;
                hi = (k < KPN) ? f2bf(w[(k * FI + f) * FO + n]) : 0u;
            }
            p[jj] = lo | (hi << 16);
        }
        unsigned int* op = (unsigned int*)&Bsw[tid * 8];
        op[0] = p[0]; op[1] = p[1]; op[2] = p[2]; op[3] = p[3];
    } else {
        const int tid = (b - 2304) * 256 + t;     // 12288 total
        const int lane = tid & 63;
        const int kt   = (tid >> 6) & 63;
        const int nt   = tid >> 12;
        const int o    = nt * 16 + (lane & 15);
        const int kbase = kt * 32 + (lane >> 4) * 8;
        #pragma unroll
        for (int j = 0; j < 8; j++) {
            const int kf = kbase + j;
            const int f = kf >> 4, k = kf & 15;
            float v = (k < KPN && o < OD) ? dw[(k * FI + f) * OD + o] : 0.f;
            unsigned short h = f2bf(v);
            dhi[tid * 8 + j] = h;
            dlo[tid * 8 + j] = f2bf(v - bf2f(h));
        }
    }
}

// ------------------------- fused main kernel -------------------------
// E=8 queries/block, 512 threads (8 waves), 2048 blocks. LDS ~74.6 KB -> 2 blocks/CU.
// B: wf0 split-bf16 MFMA (feature frags cached in regs)
// C: offsets GEMV (split-bf16 MFMA) -> dk_s in LDS
// D: wf1 MFMA (reuses cached feature frags) -> wfA_hi overwrite
// E: out[8 x 256] = wf1[8 x 2048] * Bsw[2048 x 256]
__global__ __launch_bounds__(512, 4)
void k_fused(const float* __restrict__ query, const float* __restrict__ support,
             const int* __restrict__ neighbors, const unsigned int* __restrict__ featpk,
             const float* __restrict__ kpoints,
             const unsigned short* __restrict__ dwB_hi,
             const unsigned short* __restrict__ dwB_lo,
             const unsigned short* __restrict__ Bsw,
             const float* __restrict__ bias, float* __restrict__ out)
{
    __shared__ unsigned short wfA_hi[8 * WFA_STRIDE];   // 32896 B
    __shared__ unsigned short wfA_lo[8 * WFA_STRIDE];   // 32896 B
    __shared__ float relx[256], rely[256], relz[256];   // 3072 B
    __shared__ int   nbr_s[256];                        // 1024 B
    __shared__ float kp_s[48];                          // 192 B
    __shared__ f32x4 cred[3 * 64];                      // 3072 B
    __shared__ float dk_s[8 * 45];                      // 1440 B

    const int t = threadIdx.x;
    const int qbase = blockIdx.x * 8;
    if (t < 45) kp_s[t] = kpoints[t];
    if (t >= 45 && t < 48) kp_s[t] = 0.f;

    if (t < 256) {
        const int e = t >> 5, n = t & 31;
        const int q = qbase + e;
        const int idx = neighbors[q * NN + n];
        nbr_s[t] = idx;
        relx[t] = support[idx * 3 + 0] - query[q * 3 + 0];
        rely[t] = support[idx * 3 + 1] - query[q * 3 + 1];
        relz[t] = support[idx * 3 + 2] - query[q * 3 + 2];
    }
    __syncthreads();

    const int wave = t >> 6, lane = t & 63;
    const int quad = lane >> 4, low = lane & 15;
    const int kb = (low < KPN) ? low * 3 : 0;

    unsigned int bhc[8][4];   // cached hi-part feature B-fragments (reused in Phase D)

    // ---- Phase B: wf0[ee][kf] = sum_n w0 * feat  (split-bf16, fp32 C); ee = wave
    {
        const int ee = wave;
        const float kx = kp_s[kb + 0], ky = kp_s[kb + 1], kz = kp_s[kb + 2];
        union { unsigned short u[8]; bf16x8 v; } ah, al;
        int rows[8];
        #pragma unroll
        for (int j = 0; j < 8; j++) {
            const int ni = ee * 32 + quad * 8 + j;
            rows[j] = nbr_s[ni];
            const float dx = relx[ni] - kx;
            const float dy = rely[ni] - ky;
            const float dz = relz[ni] - kz;
            const float d = sqrtf(dx * dx + dy * dy + dz * dz);
            float w = 1.0f - d * INV_EXT;
            w = (low < KPN && w > 0.f) ? w : 0.f;
            const unsigned short h = f2bf(w);
            ah.u[j] = h;
            al.u[j] = f2bf(w - bf2f(h));
        }
        #pragma unroll
        for (int ft = 0; ft < 8; ft++) {
            union { unsigned int u[4]; bf16x8 v; } bh, bl;
            #pragma unroll
            for (int jj = 0; jj < 4; jj++) {
                const unsigned int d0 = featpk[rows[2 * jj] * FI + ft * 16 + low];
                const unsigned int d1 = featpk[rows[2 * jj + 1] * FI + ft * 16 + low];
                bh.u[jj] = __builtin_amdgcn_perm(d1, d0, 0x05040100u);  // hi bf16 parts
                bl.u[jj] = __builtin_amdgcn_perm(d1, d0, 0x07060302u);  // lo bf16 parts
                bhc[ft][jj] = bh.u[jj];
            }
            f32x4 acc = {0.f, 0.f, 0.f, 0.f};
            acc = __builtin_amdgcn_mfma_f32_16x16x32_bf16(al.v, bh.v, acc, 0, 0, 0);
            acc = __builtin_amdgcn_mfma_f32_16x16x32_bf16(ah.v, bl.v, acc, 0, 0, 0);
            acc = __builtin_amdgcn_mfma_f32_16x16x32_bf16(ah.v, bh.v, acc, 0, 0, 0);
            const int kfb = (ft * 16 + low) * 16 + quad * 4;   // kf = f*16+k'
            const unsigned short h0 = f2bf(acc[0]), h1 = f2bf(acc[1]);
            const unsigned short h2 = f2bf(acc[2]), h3 = f2bf(acc[3]);
            unsigned int* ph = (unsigned int*)&wfA_hi[ee * WFA_STRIDE + kfb];
            ph[0] = (unsigned int)h0 | ((unsigned int)h1 << 16);
            ph[1] = (unsigned int)h2 | ((unsigned int)h3 << 16);
            unsigned int* pl = (unsigned int*)&wfA_lo[ee * WFA_STRIDE + kfb];
            pl[0] = (unsigned int)f2bf(acc[0] - bf2f(h0)) |
                    ((unsigned int)f2bf(acc[1] - bf2f(h1)) << 16);
            pl[1] = (unsigned int)f2bf(acc[2] - bf2f(h2)) |
                    ((unsigned int)f2bf(acc[3] - bf2f(h3)) << 16);
        }
    }
    __syncthreads();

    // ---- Phase C: feat0[8e x 48o] = wfA[8e x 2048] * dwB[2048 x 48] (split-bf16)
    // 6 waves: nt = wave>>1, half = wave&1 (32 kt each); reduce via cred.
    {
        f32x4 acc = {0.f, 0.f, 0.f, 0.f};
        const int nt = wave >> 1, half = wave & 1;
        if (wave < 6) {
            const bf16x8* Bh = (const bf16x8*)dwB_hi;
            const bf16x8* Bl = (const bf16x8*)dwB_lo;
            const int arow = (low & 7) * WFA_STRIDE;
            const int kt0 = half * 32;
            for (int kt = kt0; kt < kt0 + 32; kt++) {
                bf16x8 a_h = *(const bf16x8*)&wfA_hi[arow + kt * 32 + quad * 8];
                bf16x8 a_l = *(const bf16x8*)&wfA_lo[arow + kt * 32 + quad * 8];
                bf16x8 b_h = Bh[(nt * KT2 + kt) * 64 + lane];
                bf16x8 b_l = Bl[(nt * KT2 + kt) * 64 + lane];
                acc = __builtin_amdgcn_mfma_f32_16x16x32_bf16(a_l, b_h, acc, 0, 0, 0);
                acc = __builtin_amdgcn_mfma_f32_16x16x32_bf16(a_h, b_l, acc, 0, 0, 0);
                acc = __builtin_amdgcn_mfma_f32_16x16x32_bf16(a_h, b_h, acc, 0, 0, 0);
            }
            if (half == 1) cred[nt * 64 + lane] = acc;
        } else if (wave == 6 && lane < 24) {
            dk_s[(lane / 3) * 45 + (lane % 3)] = kp_s[lane % 3];
        }
        __syncthreads();
        if (wave < 6 && half == 0) {
            f32x4 o2 = cred[nt * 64 + lane];
            acc[0] += o2[0]; acc[1] += o2[1]; acc[2] += o2[2]; acc[3] += o2[3];
            const int o = nt * 16 + low;
            if (quad < 2 && o < OD) {
                const float bo = bias[o] + kp_s[3 + o];
                #pragma unroll
                for (int r = 0; r < 4; r++) {
                    const int ee = quad * 4 + r;
                    dk_s[ee * 45 + 3 + o] = bo + acc[r];
                }
            }
        }
    }
    __syncthreads();

    // ---- Phase D: wf1[ee][kf] via MFMA, reusing cached feature fragments
    {
        const int ee = wave;
        const float kx = dk_s[ee * 45 + kb + 0];
        const float ky = dk_s[ee * 45 + kb + 1];
        const float kz = dk_s[ee * 45 + kb + 2];
        union { unsigned short u[8]; bf16x8 v; } a1;
        #pragma unroll
        for (int j = 0; j < 8; j++) {
            const int ni = ee * 32 + quad * 8 + j;
            const float dx = relx[ni] - kx;
            const float dy = rely[ni] - ky;
            const float dz = relz[ni] - kz;
            const float d = sqrtf(dx * dx + dy * dy + dz * dz);
            float w = 1.0f - d * INV_EXT;
            w = (low < KPN && w > 0.f) ? w : 0.f;
            a1.u[j] = f2bf(w);
        }
        #pragma unroll
        for (int ft = 0; ft < 8; ft++) {
            union { unsigned int u[4]; bf16x8 v; } b;
            b.u[0] = bhc[ft][0]; b.u[1] = bhc[ft][1];
            b.u[2] = bhc[ft][2]; b.u[3] = bhc[ft][3];
            f32x4 acc = {0.f, 0.f, 0.f, 0.f};
            acc = __builtin_amdgcn_mfma_f32_16x16x32_bf16(a1.v, b.v, acc, 0, 0, 0);
            const int kfb = (ft * 16 + low) * 16 + quad * 4;
            unsigned int* wp = (unsigned int*)&wfA_hi[ee * WFA_STRIDE + kfb];
            wp[0] = (unsigned int)f2bf(acc[0]) | ((unsigned int)f2bf(acc[1]) << 16);
            wp[1] = (unsigned int)f2bf(acc[2]) | ((unsigned int)f2bf(acc[3]) << 16);
        }
    }
    __syncthreads();

    // ---- Phase E: out[8 x 256] = wf1[8 x 2048] * Bsw[2048 x 256]
    {
        const int nt0 = wave * 2, nt1 = nt0 + 1;
        f32x4 acc0 = {0.f, 0.f, 0.f, 0.f}, acc1 = {0.f, 0.f, 0.f, 0.f};
        const bf16x8* Bp = (const bf16x8*)Bsw;
        const int arow = (low & 7) * WFA_STRIDE;
        for (int kt = 0; kt < KT2; kt++) {
            bf16x8 a  = *(const bf16x8*)&wfA_hi[arow + kt * 32 + quad * 8];
            bf16x8 b0 = Bp[(nt0 * KT2 + kt) * 64 + lane];
            bf16x8 b1 = Bp[(nt1 * KT2 + kt) * 64 + lane];
            acc0 = __builtin_amdgcn_mfma_f32_16x16x32_bf16(a, b0, acc0, 0, 0, 0);
            acc1 = __builtin_amdgcn_mfma_f32_16x16x32_bf16(a, b1, acc1, 0, 0, 0);
        }
        if (quad < 2) {   // C rows 8-15 duplicate 0-7
            #pragma unroll
            for (int r = 0; r < 4; r++) {
                const int ee = quad * 4 + r;
                out[(qbase + ee) * FO + nt0 * 16 + low] = acc0[r];
                out[(qbase + ee) * FO + nt1 * 16 + low] = acc1[r];
            }
        }
    }
}

// -------------------------------------------------------------------------
extern "C" void kernel_launch(void* const* d_in, const int* in_sizes, int n_in,
                              void* d_out, int out_size, void* d_ws, size_t ws_size,
                              hipStream_t stream) {
    const float* query     = (const float*)d_in[0];
    const float* support   = (const float*)d_in[1];
    const int*   neighbors = (const int*)  d_in[2];
    const float* features  = (const float*)d_in[3];
    const float* kpoints   = (const float*)d_in[4];
    const float* weight    = (const float*)d_in[5];
    const float* dweight   = (const float*)d_in[6];
    const float* bias      = (const float*)d_in[7];
    float*       out       = (float*)d_out;

    char* ws = (char*)d_ws;
    unsigned int*   featpk = (unsigned int*)(ws + WS_FEATPK);
    unsigned short* Bsw    = (unsigned short*)(ws + WS_BSW);
    unsigned short* dwBh   = (unsigned short*)(ws + WS_DWBH);
    unsigned short* dwBl   = (unsigned short*)(ws + WS_DWBL);

    pre_all<<<2352, 256, 0, stream>>>(features, featpk, weight, Bsw,
                                      dweight, dwBh, dwBl);
    k_fused<<<NQ / 8, 512, 0, stream>>>(query, support, neighbors, featpk,
                                        kpoints, dwBh, dwBl, Bsw, bias, out);
}

// Round 7
// 212.324 us; speedup vs baseline: 1.0001x; 1.0001x over previous
//
#include <hip/hip_runtime.h>
#include <hip/hip_bf16.h>
#include <math.h>

typedef __attribute__((ext_vector_type(8))) short bf16x8;
typedef __attribute__((ext_vector_type(4))) float f32x4;

#define NQ 16384
#define NN 32
#define FI 128
#define FO 256
#define KPN 15
#define OD 42
#define INV_EXT 0.5f

#define KT2 64            // 2048 / 32
#define WFA_STRIDE 2056   // halfwords per A row: 2048 + 8 pad (4112 B)

// ws layout (bytes)
#define WS_BSW  0u                       // 16*64*64*8 bf16 = 1 MB
#define WS_DWBH (1u * 1024u * 1024u)     // 196,608
#define WS_DWBL (WS_DWBH + 196608u)

static __device__ __forceinline__ unsigned short f2bf(float x) {
    union { __hip_bfloat16 h; unsigned short u; } cv;
    cv.h = __float2bfloat16(x);
    return cv.u;
}
static __device__ __forceinline__ float bf2f(unsigned short h) {
    union { unsigned int u; float f; } cv;
    cv.u = ((unsigned int)h) << 16;
    return cv.f;
}

// ------------------------- pre-kernel: Bsw + dwB fragments -------------------------
// blocks [0,256): weight -> Bsw B-fragments (kf = f*16+k)
// blocks [256,304): dweight -> split dwB_{hi,lo} B-fragments
__global__ void pre_all(const float* __restrict__ w, unsigned short* __restrict__ Bsw,
                        const float* __restrict__ dw,
                        unsigned short* __restrict__ dhi, unsigned short* __restrict__ dlo)
{
    const int b = blockIdx.x, t = threadIdx.x;
    if (b < 256) {
        const int tid = b * 256 + t;              // 65536 total
        const int lane = tid & 63;
        const int kt   = (tid >> 6) & 63;
        const int nt   = tid >> 12;
        const int n    = nt * 16 + (lane & 15);
        const int kbase = kt * 32 + (lane >> 4) * 8;
        unsigned int p[4];
        #pragma unroll
        for (int jj = 0; jj < 4; jj++) {
            unsigned int lo, hi;
            {
                const int kk = kbase + 2 * jj;
                const int f = kk >> 4, k = kk & 15;
                lo = (k < KPN) ? f2bf(w[(k * FI + f) * FO + n]) : 0u;
            }
            {
                const int kk = kbase + 2 * jj + 1;
                const int f = kk >> 4, k = kk & 15;
                hi = (k < KPN) ? f2bf(w[(k * FI + f) * FO + n]) : 0u;
            }
            p[jj] = lo | (hi << 16);
        }
        unsigned int* op = (unsigned int*)&Bsw[tid * 8];
        op[0] = p[0]; op[1] = p[1]; op[2] = p[2]; op[3] = p[3];
    } else {
        const int tid = (b - 256) * 256 + t;      // 12288 total
        const int lane = tid & 63;
        const int kt   = (tid >> 6) & 63;
        const int nt   = tid >> 12;
        const int o    = nt * 16 + (lane & 15);
        const int kbase = kt * 32 + (lane >> 4) * 8;
        #pragma unroll
        for (int j = 0; j < 8; j++) {
            const int kf = kbase + j;
            const int f = kf >> 4, k = kf & 15;
            float v = (k < KPN && o < OD) ? dw[(k * FI + f) * OD + o] : 0.f;
            unsigned short h = f2bf(v);
            dhi[tid * 8 + j] = h;
            dlo[tid * 8 + j] = f2bf(v - bf2f(h));
        }
    }
}

// ------------------------- fused main kernel -------------------------
// E=16 queries/block, 1024 threads (16 waves), 1024 blocks, 1 block/CU.
// Stage 1 in two passes (q0-7, q8-15) sharing an 8-row wf0-lo buffer;
// wf1-hi lives in the 16-row wfA. Phase E: wave = nt slice, full M=16 tile.
__global__ __launch_bounds__(1024, 4)
void k_fused(const float* __restrict__ query, const float* __restrict__ support,
             const int* __restrict__ neighbors, const float* __restrict__ features,
             const float* __restrict__ kpoints,
             const unsigned short* __restrict__ dwB_hi,
             const unsigned short* __restrict__ dwB_lo,
             const unsigned short* __restrict__ Bsw,
             const float* __restrict__ bias, float* __restrict__ out)
{
    __shared__ unsigned short wfA_hi[16 * WFA_STRIDE];  // 65792 B (wf0-hi then wf1-hi)
    __shared__ unsigned short wfA_lo[8 * WFA_STRIDE];   // 32896 B (wf0-lo, per pass)
    __shared__ float relx[512], rely[512], relz[512];   // 6144 B
    __shared__ int   nbr_s[512];                        // 2048 B
    __shared__ float kp_s[48];                          // 192 B
    __shared__ f32x4 cred[9 * 64];                      // 9216 B
    __shared__ float dk_s[16 * 45];                     // 2880 B
    // total 119,168 B -> 1 block/CU, 16 waves

    const int t = threadIdx.x;
    const int qbase = blockIdx.x * 16;
    if (t < 45) kp_s[t] = kpoints[t];
    if (t >= 45 && t < 48) kp_s[t] = 0.f;

    if (t < 512) {
        const int e = t >> 5, n = t & 31;
        const int q = qbase + e;
        const int idx = neighbors[q * NN + n];
        nbr_s[t] = idx;
        relx[t] = support[idx * 3 + 0] - query[q * 3 + 0];
        rely[t] = support[idx * 3 + 1] - query[q * 3 + 1];
        relz[t] = support[idx * 3 + 2] - query[q * 3 + 2];
    }
    __syncthreads();

    const int wave = t >> 6, lane = t & 63;
    const int quad = lane >> 4, low = lane & 15;
    const int kb   = (low < KPN) ? low * 3 : 0;
    const int qloc = wave & 7;           // query-within-half this wave serves
    const int fts  = (wave >> 3) * 4;    // ft-half: waves 0-7 -> ft 0..3, 8-15 -> 4..7

    unsigned int bhc[2][4][4];           // cached RNE-hi feature fragments (for Phase D)

    // ================= stage 1: two passes (B then C) =================
    for (int pass = 0; pass < 2; pass++) {
        // ---- Phase B: wf0[qq][kf] = sum_n w0 * feat  (split-bf16, fp32 C)
        {
            const int qq = pass * 8 + qloc;
            const float kx = kp_s[kb + 0], ky = kp_s[kb + 1], kz = kp_s[kb + 2];
            union { unsigned short u[8]; bf16x8 v; } ah, al;
            int rows[8];
            #pragma unroll
            for (int j = 0; j < 8; j++) {
                const int ni = qq * 32 + quad * 8 + j;
                rows[j] = nbr_s[ni];
                const float dx = relx[ni] - kx;
                const float dy = rely[ni] - ky;
                const float dz = relz[ni] - kz;
                const float d = sqrtf(dx * dx + dy * dy + dz * dz);
                float w = 1.0f - d * INV_EXT;
                w = (low < KPN && w > 0.f) ? w : 0.f;
                const unsigned short h = f2bf(w);
                ah.u[j] = h;
                al.u[j] = f2bf(w - bf2f(h));
            }
            #pragma unroll
            for (int fi = 0; fi < 4; fi++) {
                const int ft = fts + fi;
                union { unsigned int u[4]; bf16x8 v; } bh, bl;
                #pragma unroll
                for (int jj = 0; jj < 4; jj++) {
                    const float d0 = features[rows[2 * jj] * FI + ft * 16 + low];
                    const float d1 = features[rows[2 * jj + 1] * FI + ft * 16 + low];
                    float2 fv; fv.x = d0; fv.y = d1;
                    union { __hip_bfloat162 h2; unsigned int u; } hh;
                    hh.h2 = __float22bfloat162_rn(fv);
                    bh.u[jj] = hh.u;
                    bhc[pass][fi][jj] = hh.u;
                    union { unsigned int u; float f; } t0, t1;
                    t0.u = hh.u << 16;
                    t1.u = hh.u & 0xffff0000u;
                    float2 rv; rv.x = d0 - t0.f; rv.y = d1 - t1.f;
                    union { __hip_bfloat162 h2; unsigned int u; } ll;
                    ll.h2 = __float22bfloat162_rn(rv);
                    bl.u[jj] = ll.u;
                }
                f32x4 acc = {0.f, 0.f, 0.f, 0.f};
                acc = __builtin_amdgcn_mfma_f32_16x16x32_bf16(al.v, bh.v, acc, 0, 0, 0);
                acc = __builtin_amdgcn_mfma_f32_16x16x32_bf16(ah.v, bl.v, acc, 0, 0, 0);
                acc = __builtin_amdgcn_mfma_f32_16x16x32_bf16(ah.v, bh.v, acc, 0, 0, 0);
                const int kfb = (ft * 16 + low) * 16 + quad * 4;   // kf = f*16+k'
                const unsigned short h0 = f2bf(acc[0]), h1 = f2bf(acc[1]);
                const unsigned short h2 = f2bf(acc[2]), h3 = f2bf(acc[3]);
                unsigned int* ph = (unsigned int*)&wfA_hi[qq * WFA_STRIDE + kfb];
                ph[0] = (unsigned int)h0 | ((unsigned int)h1 << 16);
                ph[1] = (unsigned int)h2 | ((unsigned int)h3 << 16);
                unsigned int* pl = (unsigned int*)&wfA_lo[qloc * WFA_STRIDE + kfb];
                pl[0] = (unsigned int)f2bf(acc[0] - bf2f(h0)) |
                        ((unsigned int)f2bf(acc[1] - bf2f(h1)) << 16);
                pl[1] = (unsigned int)f2bf(acc[2] - bf2f(h2)) |
                        ((unsigned int)f2bf(acc[3] - bf2f(h3)) << 16);
            }
        }
        __syncthreads();

        // ---- Phase C: feat0[8 x 48] = wf0[8 x 2048] * dwB[2048 x 48] (split-bf16)
        // 12 waves: nt = wave&3 (<3), qr = wave>>2 (16 kt each); reduce via cred.
        {
            f32x4 acc = {0.f, 0.f, 0.f, 0.f};
            const int nt = wave & 3, qr = wave >> 2;
            if (nt < 3) {
                const bf16x8* Bh = (const bf16x8*)dwB_hi;
                const bf16x8* Bl = (const bf16x8*)dwB_lo;
                const int arow_h = (pass * 8 + (low & 7)) * WFA_STRIDE;
                const int arow_l = (low & 7) * WFA_STRIDE;
                const int kt0 = qr * 16;
                for (int kt = kt0; kt < kt0 + 16; kt++) {
                    bf16x8 a_h = *(const bf16x8*)&wfA_hi[arow_h + kt * 32 + quad * 8];
                    bf16x8 a_l = *(const bf16x8*)&wfA_lo[arow_l + kt * 32 + quad * 8];
                    bf16x8 b_h = Bh[(nt * KT2 + kt) * 64 + lane];
                    bf16x8 b_l = Bl[(nt * KT2 + kt) * 64 + lane];
                    acc = __builtin_amdgcn_mfma_f32_16x16x32_bf16(a_l, b_h, acc, 0, 0, 0);
                    acc = __builtin_amdgcn_mfma_f32_16x16x32_bf16(a_h, b_l, acc, 0, 0, 0);
                    acc = __builtin_amdgcn_mfma_f32_16x16x32_bf16(a_h, b_h, acc, 0, 0, 0);
                }
                if (qr > 0) cred[(nt * 3 + qr - 1) * 64 + lane] = acc;
            } else if (pass == 0 && wave == 3 && lane < 48) {
                dk_s[(lane / 3) * 45 + (lane % 3)] = kp_s[lane % 3];
            }
            __syncthreads();
            if (nt < 3 && qr == 0) {
                #pragma unroll
                for (int s = 0; s < 3; s++) {
                    f32x4 o2 = cred[(nt * 3 + s) * 64 + lane];
                    acc[0] += o2[0]; acc[1] += o2[1]; acc[2] += o2[2]; acc[3] += o2[3];
                }
                const int o = nt * 16 + low;
                if (quad < 2 && o < OD) {
                    const float bo = bias[o] + kp_s[3 + o];
                    #pragma unroll
                    for (int r = 0; r < 4; r++) {
                        const int ee = pass * 8 + quad * 4 + r;   // C row -> query
                        dk_s[ee * 45 + 3 + o] = bo + acc[r];
                    }
                }
            }
        }
        __syncthreads();
    }

    // ---- Phase D: wf1[qq][kf] single-product MFMA, reusing cached feature frags
    #pragma unroll
    for (int pass = 0; pass < 2; pass++) {
        const int qq = pass * 8 + qloc;
        const float kx = dk_s[qq * 45 + kb + 0];
        const float ky = dk_s[qq * 45 + kb + 1];
        const float kz = dk_s[qq * 45 + kb + 2];
        union { unsigned short u[8]; bf16x8 v; } a1;
        #pragma unroll
        for (int j = 0; j < 8; j++) {
            const int ni = qq * 32 + quad * 8 + j;
            const float dx = relx[ni] - kx;
            const float dy = rely[ni] - ky;
            const float dz = relz[ni] - kz;
            const float d = sqrtf(dx * dx + dy * dy + dz * dz);
            float w = 1.0f - d * INV_EXT;
            w = (low < KPN && w > 0.f) ? w : 0.f;
            a1.u[j] = f2bf(w);
        }
        #pragma unroll
        for (int fi = 0; fi < 4; fi++) {
            const int ft = fts + fi;
            union { unsigned int u[4]; bf16x8 v; } b;
            b.u[0] = bhc[pass][fi][0]; b.u[1] = bhc[pass][fi][1];
            b.u[2] = bhc[pass][fi][2]; b.u[3] = bhc[pass][fi][3];
            f32x4 acc = {0.f, 0.f, 0.f, 0.f};
            acc = __builtin_amdgcn_mfma_f32_16x16x32_bf16(a1.v, b.v, acc, 0, 0, 0);
            const int kfb = (ft * 16 + low) * 16 + quad * 4;
            unsigned int* wp = (unsigned int*)&wfA_hi[qq * WFA_STRIDE + kfb];
            wp[0] = (unsigned int)f2bf(acc[0]) | ((unsigned int)f2bf(acc[1]) << 16);
            wp[1] = (unsigned int)f2bf(acc[2]) | ((unsigned int)f2bf(acc[3]) << 16);
        }
    }
    __syncthreads();

    // ---- Phase E: out[16 x 256] = wf1[16 x 2048] * Bsw[2048 x 256]
    // wave = nt slice (16 waves, full M=16 tile), rolling prefetch.
    {
        const int nt = wave;
        f32x4 acc = {0.f, 0.f, 0.f, 0.f};
        const bf16x8* Bp = (const bf16x8*)Bsw;
        const int arow = low * WFA_STRIDE;
        bf16x8 a_c = *(const bf16x8*)&wfA_hi[arow + quad * 8];
        bf16x8 b_c = Bp[(nt * KT2) * 64 + lane];
        for (int kt = 0; kt < KT2 - 1; kt++) {
            bf16x8 a_n = *(const bf16x8*)&wfA_hi[arow + (kt + 1) * 32 + quad * 8];
            bf16x8 b_n = Bp[(nt * KT2 + kt + 1) * 64 + lane];
            acc = __builtin_amdgcn_mfma_f32_16x16x32_bf16(a_c, b_c, acc, 0, 0, 0);
            a_c = a_n; b_c = b_n;
        }
        acc = __builtin_amdgcn_mfma_f32_16x16x32_bf16(a_c, b_c, acc, 0, 0, 0);
        #pragma unroll
        for (int r = 0; r < 4; r++) {
            const int ee = quad * 4 + r;
            out[(qbase + ee) * FO + nt * 16 + low] = acc[r];
        }
    }
}

// -------------------------------------------------------------------------
extern "C" void kernel_launch(void* const* d_in, const int* in_sizes, int n_in,
                              void* d_out, int out_size, void* d_ws, size_t ws_size,
                              hipStream_t stream) {
    const float* query     = (const float*)d_in[0];
    const float* support   = (const float*)d_in[1];
    const int*   neighbors = (const int*)  d_in[2];
    const float* features  = (const float*)d_in[3];
    const float* kpoints   = (const float*)d_in[4];
    const float* weight    = (const float*)d_in[5];
    const float* dweight   = (const float*)d_in[6];
    const float* bias      = (const float*)d_in[7];
    float*       out       = (float*)d_out;

    char* ws = (char*)d_ws;
    unsigned short* Bsw  = (unsigned short*)(ws + WS_BSW);
    unsigned short* dwBh = (unsigned short*)(ws + WS_DWBH);
    unsigned short* dwBl = (unsigned short*)(ws + WS_DWBL);

    pre_all<<<304, 256, 0, stream>>>(weight, Bsw, dweight, dwBh, dwBl);
    k_fused<<<NQ / 16, 1024, 0, stream>>>(query, support, neighbors, features,
                                          kpoints, dwBh, dwBl, Bsw, bias, out);
}

// Round 8
// 197.197 us; speedup vs baseline: 1.0768x; 1.0767x over previous
//
#include <hip/hip_runtime.h>
#include <hip/hip_bf16.h>
#include <math.h>

typedef __attribute__((ext_vector_type(8))) short bf16x8;
typedef __attribute__((ext_vector_type(4))) float f32x4;

#define NQ 16384
#define NN 32
#define FI 128
#define FO 256
#define KPN 15
#define OD 42
#define INV_EXT 0.5f

#define KT2 64            // 2048 / 32
#define WST 2048          // wfA row stride in halfwords; banks handled by XOR swizzle

// 64B-block XOR swizzle within a wfA row (units: halfwords; 32 hw = 64 B block)
#define SWZ(row, blk) (((blk) ^ ((row) & 7)) << 5)

// ws layout (bytes)
#define WS_FEATPK 0u                      // 16384*128 u32 (hi|lo<<16) = 8 MB
#define WS_BSW    (8u * 1024u * 1024u)    // 1 MB
#define WS_DWBH   (9u * 1024u * 1024u)    // 196,608
#define WS_DWBL   (WS_DWBH + 196608u)     // 196,608
#define WS_DEFKP  (10u * 1024u * 1024u)   // 16384*45*4 = 2.95 MB

static __device__ __forceinline__ unsigned short f2bf(float x) {
    union { __hip_bfloat16 h; unsigned short u; } cv;
    cv.h = __float2bfloat16(x);
    return cv.u;
}
static __device__ __forceinline__ float bf2f(unsigned short h) {
    union { unsigned int u; float f; } cv;
    cv.u = ((unsigned int)h) << 16;
    return cv.f;
}

// ------------------------- fused pre-kernel -------------------------
// blocks [0,2048): features -> featpk (hi | lo<<16)
// blocks [2048,2304): weight -> Bsw B-fragments (kf = f*16+k)
// blocks [2304,2352): dweight -> split dwB_{hi,lo} B-fragments
__global__ void pre_all(const float* __restrict__ feat, unsigned int* __restrict__ fpk,
                        const float* __restrict__ w, unsigned short* __restrict__ Bsw,
                        const float* __restrict__ dw,
                        unsigned short* __restrict__ dhi, unsigned short* __restrict__ dlo)
{
    const int b = blockIdx.x, t = threadIdx.x;
    if (b < 2048) {
        const int i = (b * 256 + t) * 4;
        float4 a = *(const float4*)&feat[i];
        unsigned short h0 = f2bf(a.x), h1 = f2bf(a.y), h2 = f2bf(a.z), h3 = f2bf(a.w);
        fpk[i + 0] = (unsigned int)h0 | ((unsigned int)f2bf(a.x - bf2f(h0)) << 16);
        fpk[i + 1] = (unsigned int)h1 | ((unsigned int)f2bf(a.y - bf2f(h1)) << 16);
        fpk[i + 2] = (unsigned int)h2 | ((unsigned int)f2bf(a.z - bf2f(h2)) << 16);
        fpk[i + 3] = (unsigned int)h3 | ((unsigned int)f2bf(a.w - bf2f(h3)) << 16);
    } else if (b < 2048 + 256) {
        const int tid = (b - 2048) * 256 + t;     // 65536 total
        const int lane = tid & 63;
        const int kt   = (tid >> 6) & 63;
        const int nt   = tid >> 12;
        const int n    = nt * 16 + (lane & 15);
        const int kbase = kt * 32 + (lane >> 4) * 8;
        unsigned int p[4];
        #pragma unroll
        for (int jj = 0; jj < 4; jj++) {
            unsigned int lo, hi;
            {
                const int kk = kbase + 2 * jj;
                const int f = kk >> 4, k = kk & 15;
                lo = (k < KPN) ? f2bf(w[(k * FI + f) * FO + n]) : 0u;
            }
            {
                const int kk = kbase + 2 * jj + 1;
                const int f = kk >> 4, k = kk & 15;
                hi = (k < KPN) ? f2bf(w[(k * FI + f) * FO + n]) : 0u;
            }
            p[jj] = lo | (hi << 16);
        }
        unsigned int* op = (unsigned int*)&Bsw[tid * 8];
        op[0] = p[0]; op[1] = p[1]; op[2] = p[2]; op[3] = p[3];
    } else {
        const int tid = (b - 2304) * 256 + t;     // 12288 total
        const int lane = tid & 63;
        const int kt   = (tid >> 6) & 63;
        const int nt   = tid >> 12;
        const int o    = nt * 16 + (lane & 15);
        const int kbase = kt * 32 + (lane >> 4) * 8;
        #pragma unroll
        for (int j = 0; j < 8; j++) {
            const int kf = kbase + j;
            const int f = kf >> 4, k = kf & 15;
            float v = (k < KPN && o < OD) ? dw[(k * FI + f) * OD + o] : 0.f;
            unsigned short h = f2bf(v);
            dhi[tid * 8 + j] = h;
            dlo[tid * 8 + j] = f2bf(v - bf2f(h));
        }
    }
}

// ------------------------- stage 1: offsets via split-bf16 MFMA -------------------------
// E=8 queries/block, 512 threads (8 waves). LDS ~74 KB -> 2 blocks/CU = 16 waves/CU.
__global__ __launch_bounds__(512, 4)
void k1_offsets(const float* __restrict__ query, const float* __restrict__ support,
                const int* __restrict__ neighbors, const unsigned int* __restrict__ featpk,
                const float* __restrict__ kpoints,
                const unsigned short* __restrict__ dwB_hi,
                const unsigned short* __restrict__ dwB_lo,
                const float* __restrict__ bias, float* __restrict__ defkp)
{
    __shared__ unsigned short wfA_hi[8 * WST];          // 32768 B
    __shared__ unsigned short wfA_lo[8 * WST];          // 32768 B
    __shared__ float relx[256], rely[256], relz[256];   // 3072 B
    __shared__ int   nbr_s[256];                        // 1024 B
    __shared__ float kp_s[48];                          // 192 B
    __shared__ f32x4 cred[3 * 64];                      // 3072 B

    const int t = threadIdx.x;
    const int qbase = blockIdx.x * 8;
    if (t < 45) kp_s[t] = kpoints[t];
    if (t >= 45 && t < 48) kp_s[t] = 0.f;

    if (t < 256) {
        const int e = t >> 5, n = t & 31;
        const int q = qbase + e;
        const int idx = neighbors[q * NN + n];
        nbr_s[t] = idx;
        relx[t] = support[idx * 3 + 0] - query[q * 3 + 0];
        rely[t] = support[idx * 3 + 1] - query[q * 3 + 1];
        relz[t] = support[idx * 3 + 2] - query[q * 3 + 2];
    }
    __syncthreads();

    const int wave = t >> 6, lane = t & 63;
    const int quad = lane >> 4, low = lane & 15;

    // Phase B: wf0[ee][kf] = sum_n w0 * feat  (split-bf16, fp32 C); ee = wave
    {
        const int ee = wave;
        const int kb = (low < KPN) ? low * 3 : 0;
        const float kx = kp_s[kb + 0], ky = kp_s[kb + 1], kz = kp_s[kb + 2];
        union { unsigned short u[8]; bf16x8 v; } ah, al;
        int rows[8];
        #pragma unroll
        for (int j = 0; j < 8; j++) {
            const int ni = ee * 32 + quad * 8 + j;
            rows[j] = nbr_s[ni];
            const float dx = relx[ni] - kx;
            const float dy = rely[ni] - ky;
            const float dz = relz[ni] - kz;
            const float d = sqrtf(dx * dx + dy * dy + dz * dz);
            float w = 1.0f - d * INV_EXT;
            w = (low < KPN && w > 0.f) ? w : 0.f;
            const unsigned short h = f2bf(w);
            ah.u[j] = h;
            al.u[j] = f2bf(w - bf2f(h));
        }
        #pragma unroll
        for (int ft = 0; ft < 8; ft++) {
            union { unsigned int u[4]; bf16x8 v; } bh, bl;
            #pragma unroll
            for (int jj = 0; jj < 4; jj++) {
                const unsigned int d0 = featpk[rows[2 * jj] * FI + ft * 16 + low];
                const unsigned int d1 = featpk[rows[2 * jj + 1] * FI + ft * 16 + low];
                bh.u[jj] = __builtin_amdgcn_perm(d1, d0, 0x05040100u);  // hi parts
                bl.u[jj] = __builtin_amdgcn_perm(d1, d0, 0x07060302u);  // lo parts
            }
            f32x4 acc = {0.f, 0.f, 0.f, 0.f};
            acc = __builtin_amdgcn_mfma_f32_16x16x32_bf16(al.v, bh.v, acc, 0, 0, 0);
            acc = __builtin_amdgcn_mfma_f32_16x16x32_bf16(ah.v, bl.v, acc, 0, 0, 0);
            acc = __builtin_amdgcn_mfma_f32_16x16x32_bf16(ah.v, bh.v, acc, 0, 0, 0);
            // C elem (row k'=quad*4+r, col f=ft*16+low) -> kf = f*16+k'; swizzled store
            const int col  = ft * 16 + low;
            const int base = ee * WST + SWZ(ee, col >> 1) + ((col & 1) << 4) + quad * 4;
            const unsigned short h0 = f2bf(acc[0]), h1 = f2bf(acc[1]);
            const unsigned short h2 = f2bf(acc[2]), h3 = f2bf(acc[3]);
            unsigned int* ph = (unsigned int*)&wfA_hi[base];
            ph[0] = (unsigned int)h0 | ((unsigned int)h1 << 16);
            ph[1] = (unsigned int)h2 | ((unsigned int)h3 << 16);
            unsigned int* pl = (unsigned int*)&wfA_lo[base];
            pl[0] = (unsigned int)f2bf(acc[0] - bf2f(h0)) |
                    ((unsigned int)f2bf(acc[1] - bf2f(h1)) << 16);
            pl[1] = (unsigned int)f2bf(acc[2] - bf2f(h2)) |
                    ((unsigned int)f2bf(acc[3] - bf2f(h3)) << 16);
        }
    }
    __syncthreads();

    // Phase C: feat0[8e x 48o] = wf0[8e x 2048] * dwB[2048 x 48]  (split-bf16)
    // 6 waves: nt = wave>>1, half = wave&1 (32 kt each); reduce via cred.
    f32x4 acc = {0.f, 0.f, 0.f, 0.f};
    const int nt = wave >> 1, half = wave & 1;
    if (wave < 6) {
        const bf16x8* Bh = (const bf16x8*)dwB_hi;
        const bf16x8* Bl = (const bf16x8*)dwB_lo;
        const int rl = low & 7;            // A row (rows 8..15 duplicate 0..7)
        const int arow = rl * WST;
        const int kt0 = half * 32;
        for (int kt = kt0; kt < kt0 + 32; kt++) {
            const int ao = arow + SWZ(rl, kt) + quad * 8;
            bf16x8 a_h = *(const bf16x8*)&wfA_hi[ao];
            bf16x8 a_l = *(const bf16x8*)&wfA_lo[ao];
            bf16x8 b_h = Bh[(nt * KT2 + kt) * 64 + lane];
            bf16x8 b_l = Bl[(nt * KT2 + kt) * 64 + lane];
            acc = __builtin_amdgcn_mfma_f32_16x16x32_bf16(a_l, b_h, acc, 0, 0, 0);
            acc = __builtin_amdgcn_mfma_f32_16x16x32_bf16(a_h, b_l, acc, 0, 0, 0);
            acc = __builtin_amdgcn_mfma_f32_16x16x32_bf16(a_h, b_h, acc, 0, 0, 0);
        }
        if (half == 1) cred[nt * 64 + lane] = acc;
    } else if (wave == 6 && lane < 24) {
        defkp[(qbase + lane / 3) * 45 + (lane % 3)] = kp_s[lane % 3];
    }
    __syncthreads();

    if (wave < 6 && half == 0) {
        f32x4 o2 = cred[nt * 64 + lane];
        acc[0] += o2[0]; acc[1] += o2[1]; acc[2] += o2[2]; acc[3] += o2[3];
        const int o = nt * 16 + low;
        if (quad < 2 && o < OD) {
            const float bo = bias[o] + kp_s[3 + o];
            #pragma unroll
            for (int r = 0; r < 4; r++) {
                const int ee = quad * 4 + r;                 // C row = e
                defkp[(qbase + ee) * 45 + 3 + o] = bo + acc[r];
            }
        }
    }
}

// ------------------------- stage 2 (bf16 MFMA): deformable conv -------------------------
// E=16 queries, 512 threads. LDS ~77 KB -> 2 blocks/CU (16 waves).
__global__ __launch_bounds__(512, 4)
void k2_deform(const float* __restrict__ query, const float* __restrict__ support,
               const int* __restrict__ neighbors, const unsigned int* __restrict__ featpk,
               const unsigned short* __restrict__ Bsw, const float* __restrict__ defkp,
               float* __restrict__ out)
{
    __shared__ unsigned short wfA[16 * WST];             // 65536 B
    __shared__ float relx[512], rely[512], relz[512];    // 6144 B
    __shared__ float dk_s[16 * 45];                      // 2880 B
    __shared__ int   nbr_s[512];                         // 2048 B

    const int t = threadIdx.x;
    const int qbase = blockIdx.x * 16;

    for (int i = t; i < 16 * 45; i += 512) dk_s[i] = defkp[qbase * 45 + i];

    const int e = t >> 5, n = t & 31;
    const int q = qbase + e;
    const int idx = neighbors[q * NN + n];
    nbr_s[t] = idx;
    relx[t] = support[idx * 3 + 0] - query[q * 3 + 0];
    rely[t] = support[idx * 3 + 1] - query[q * 3 + 1];
    relz[t] = support[idx * 3 + 2] - query[q * 3 + 2];
    __syncthreads();

    const int wave = t >> 6, lane = t & 63;
    const int quad = lane >> 4, low = lane & 15;

    // wf1 via MFMA; A-frag (w1^T) recomputed per lane from rel + def_kp
    {
        const int kb = (low < KPN) ? low * 3 : 0;
        for (int ei = 0; ei < 2; ei++) {
            const int ee = wave * 2 + ei;
            const float kx = dk_s[ee * 45 + kb + 0];
            const float ky = dk_s[ee * 45 + kb + 1];
            const float kz = dk_s[ee * 45 + kb + 2];
            union { unsigned short u[8]; bf16x8 v; } a;
            int rows[8];
            #pragma unroll
            for (int j = 0; j < 8; j++) {
                const int ni = ee * 32 + quad * 8 + j;
                rows[j] = nbr_s[ni];
                const float dx = relx[ni] - kx;
                const float dy = rely[ni] - ky;
                const float dz = relz[ni] - kz;
                const float d = sqrtf(dx * dx + dy * dy + dz * dz);
                float w = 1.0f - d * INV_EXT;
                w = (low < KPN && w > 0.f) ? w : 0.f;
                a.u[j] = f2bf(w);
            }
            #pragma unroll
            for (int ft = 0; ft < 8; ft++) {
                union { unsigned int u[4]; bf16x8 v; } b;
                #pragma unroll
                for (int jj = 0; jj < 4; jj++) {
                    const unsigned int d0 = featpk[rows[2 * jj] * FI + ft * 16 + low];
                    const unsigned int d1 = featpk[rows[2 * jj + 1] * FI + ft * 16 + low];
                    b.u[jj] = __builtin_amdgcn_perm(d1, d0, 0x05040100u);  // hi parts
                }
                f32x4 acc = {0.f, 0.f, 0.f, 0.f};
                acc = __builtin_amdgcn_mfma_f32_16x16x32_bf16(a.v, b.v, acc, 0, 0, 0);
                const int col  = ft * 16 + low;
                const int base = ee * WST + SWZ(ee, col >> 1) + ((col & 1) << 4) + quad * 4;
                unsigned int* wp = (unsigned int*)&wfA[base];
                wp[0] = (unsigned int)f2bf(acc[0]) | ((unsigned int)f2bf(acc[1]) << 16);
                wp[1] = (unsigned int)f2bf(acc[2]) | ((unsigned int)f2bf(acc[3]) << 16);
            }
        }
    }
    __syncthreads();

    // GEMM2: out[16 x 256] = wf1[16 x 2048] * Bsw[2048 x 256], rolling prefetch
    {
        const int nt0 = wave * 2, nt1 = nt0 + 1;
        f32x4 acc0 = {0.f, 0.f, 0.f, 0.f}, acc1 = {0.f, 0.f, 0.f, 0.f};
        const bf16x8* Bp = (const bf16x8*)Bsw;
        const int arow = low * WST;
        bf16x8 a_c  = *(const bf16x8*)&wfA[arow + SWZ(low, 0) + quad * 8];
        bf16x8 b0_c = Bp[(nt0 * KT2) * 64 + lane];
        bf16x8 b1_c = Bp[(nt1 * KT2) * 64 + lane];
        for (int kt = 0; kt < KT2 - 1; kt++) {
            bf16x8 a_n  = *(const bf16x8*)&wfA[arow + SWZ(low, kt + 1) + quad * 8];
            bf16x8 b0_n = Bp[(nt0 * KT2 + kt + 1) * 64 + lane];
            bf16x8 b1_n = Bp[(nt1 * KT2 + kt + 1) * 64 + lane];
            acc0 = __builtin_amdgcn_mfma_f32_16x16x32_bf16(a_c, b0_c, acc0, 0, 0, 0);
            acc1 = __builtin_amdgcn_mfma_f32_16x16x32_bf16(a_c, b1_c, acc1, 0, 0, 0);
            a_c = a_n; b0_c = b0_n; b1_c = b1_n;
        }
        acc0 = __builtin_amdgcn_mfma_f32_16x16x32_bf16(a_c, b0_c, acc0, 0, 0, 0);
        acc1 = __builtin_amdgcn_mfma_f32_16x16x32_bf16(a_c, b1_c, acc1, 0, 0, 0);
        #pragma unroll
        for (int r = 0; r < 4; r++) {
            const int ee = quad * 4 + r;
            out[(qbase + ee) * FO + nt0 * 16 + low] = acc0[r];
            out[(qbase + ee) * FO + nt1 * 16 + low] = acc1[r];
        }
    }
}

// -------------------------------------------------------------------------
extern "C" void kernel_launch(void* const* d_in, const int* in_sizes, int n_in,
                              void* d_out, int out_size, void* d_ws, size_t ws_size,
                              hipStream_t stream) {
    const float* query     = (const float*)d_in[0];
    const float* support   = (const float*)d_in[1];
    const int*   neighbors = (const int*)  d_in[2];
    const float* features  = (const float*)d_in[3];
    const float* kpoints   = (const float*)d_in[4];
    const float* weight    = (const float*)d_in[5];
    const float* dweight   = (const float*)d_in[6];
    const float* bias      = (const float*)d_in[7];
    float*       out       = (float*)d_out;

    char* ws = (char*)d_ws;
    unsigned int*   featpk = (unsigned int*)(ws + WS_FEATPK);
    unsigned short* Bsw    = (unsigned short*)(ws + WS_BSW);
    unsigned short* dwBh   = (unsigned short*)(ws + WS_DWBH);
    unsigned short* dwBl   = (unsigned short*)(ws + WS_DWBL);
    float*          defkp  = (float*)(ws + WS_DEFKP);

    pre_all<<<2352, 256, 0, stream>>>(features, featpk, weight, Bsw,
                                      dweight, dwBh, dwBl);
    k1_offsets<<<NQ / 8, 512, 0, stream>>>(query, support, neighbors, featpk,
                                           kpoints, dwBh, dwBl, bias, defkp);
    k2_deform<<<NQ / 16, 512, 0, stream>>>(query, support, neighbors, featpk,
                                           Bsw, defkp, out);
}

// Round 9
// 191.012 us; speedup vs baseline: 1.1117x; 1.0324x over previous
//
#include <hip/hip_runtime.h>
#include <hip/hip_bf16.h>
#include <math.h>

typedef __attribute__((ext_vector_type(8))) short bf16x8;
typedef __attribute__((ext_vector_type(4))) float f32x4;

#define NQ 16384
#define NN 32
#define FI 128
#define FO 256
#define KPN 15
#define OD 42
#define INV_EXT 0.5f

#define KT2 64            // 2048 / 32
#define WST 2048          // wfA row stride in halfwords; banks handled by XOR swizzle

// 64B-block XOR swizzle within a wfA row (units: halfwords; 32 hw = 64 B block)
#define SWZ(row, blk) (((blk) ^ ((row) & 7)) << 5)

// ws layout (bytes)
#define WS_FP1    0u                        // [NQ][128] u32 pair-frag hi/lo  = 8 MB
#define WS_FP2    (8u * 1024u * 1024u)      // [NQ][64]  u32 pair-frag hi     = 4 MB
#define WS_BSW    (12u * 1024u * 1024u)     // 1 MB
#define WS_DWBH   (13u * 1024u * 1024u)     // 196,608
#define WS_DWBL   (WS_DWBH + 196608u)       // 196,608
#define WS_DEFKP  (14u * 1024u * 1024u)     // 16384*45*4 = 2.95 MB

static __device__ __forceinline__ unsigned short f2bf(float x) {
    union { __hip_bfloat16 h; unsigned short u; } cv;
    cv.h = __float2bfloat16(x);
    return cv.u;
}
static __device__ __forceinline__ float bf2f(unsigned short h) {
    union { unsigned int u; float f; } cv;
    cv.u = ((unsigned int)h) << 16;
    return cv.f;
}

// ------------------------- fused pre-kernel -------------------------
// blocks [0,4096): features -> fp1 (pair-frag hi|hi / lo|lo dword pairs) + fp2 (hi pairs)
//   pair layout: for (s, fp, low): fA = fp*32+low (ft=2fp), fB = fp*32+16+low (ft=2fp+1)
//   fp1[s*128 + fp*32 + low*2]     = bfhi(fA) | bfhi(fB)<<16
//   fp1[s*128 + fp*32 + low*2 + 1] = bflo(fA) | bflo(fB)<<16
//   fp2[s*64 + fp*16 + low]        = bfhi(fA) | bfhi(fB)<<16
// blocks [4096,4352): weight -> Bsw B-fragments (kf = f*16+k)
// blocks [4352,4400): dweight -> split dwB_{hi,lo} B-fragments
__global__ void pre_all(const float* __restrict__ feat,
                        unsigned int* __restrict__ fp1, unsigned int* __restrict__ fp2,
                        const float* __restrict__ w, unsigned short* __restrict__ Bsw,
                        const float* __restrict__ dw,
                        unsigned short* __restrict__ dhi, unsigned short* __restrict__ dlo)
{
    const int b = blockIdx.x, t = threadIdx.x;
    if (b < 4096) {
        const int tid = b * 256 + t;          // 1,048,576 total = NQ*64
        const int s = tid >> 6, r = tid & 63;
        const int fp = r >> 4, low = r & 15;
        const float a = feat[s * FI + fp * 32 + low];
        const float c = feat[s * FI + fp * 32 + 16 + low];
        const unsigned short ha = f2bf(a), hc = f2bf(c);
        const unsigned int w0 = (unsigned int)ha | ((unsigned int)hc << 16);
        const unsigned int w1 = (unsigned int)f2bf(a - bf2f(ha)) |
                                ((unsigned int)f2bf(c - bf2f(hc)) << 16);
        uint2 pr; pr.x = w0; pr.y = w1;
        *(uint2*)&fp1[s * 128 + fp * 32 + low * 2] = pr;
        fp2[s * 64 + fp * 16 + low] = w0;
    } else if (b < 4096 + 256) {
        const int tid = (b - 4096) * 256 + t; // 65536 total
        const int lane = tid & 63;
        const int kt   = (tid >> 6) & 63;
        const int nt   = tid >> 12;
        const int n    = nt * 16 + (lane & 15);
        const int kbase = kt * 32 + (lane >> 4) * 8;
        unsigned int p[4];
        #pragma unroll
        for (int jj = 0; jj < 4; jj++) {
            unsigned int lo, hi;
            {
                const int kk = kbase + 2 * jj;
                const int f = kk >> 4, k = kk & 15;
                lo = (k < KPN) ? f2bf(w[(k * FI + f) * FO + n]) : 0u;
            }
            {
                const int kk = kbase + 2 * jj + 1;
                const int f = kk >> 4, k = kk & 15;
                hi = (k < KPN) ? f2bf(w[(k * FI + f) * FO + n]) : 0u;
            }
            p[jj] = lo | (hi << 16);
        }
        unsigned int* op = (unsigned int*)&Bsw[tid * 8];
        op[0] = p[0]; op[1] = p[1]; op[2] = p[2]; op[3] = p[3];
    } else {
        const int tid = (b - 4352) * 256 + t; // 12288 total
        const int lane = tid & 63;
        const int kt   = (tid >> 6) & 63;
        const int nt   = tid >> 12;
        const int o    = nt * 16 + (lane & 15);
        const int kbase = kt * 32 + (lane >> 4) * 8;
        #pragma unroll
        for (int j = 0; j < 8; j++) {
            const int kf = kbase + j;
            const int f = kf >> 4, k = kf & 15;
            float v = (k < KPN && o < OD) ? dw[(k * FI + f) * OD + o] : 0.f;
            unsigned short h = f2bf(v);
            dhi[tid * 8 + j] = h;
            dlo[tid * 8 + j] = f2bf(v - bf2f(h));
        }
    }
}

// ------------------------- stage 1: offsets via split-bf16 MFMA -------------------------
// E=8 queries/block, 512 threads (8 waves). LDS ~74 KB -> 2 blocks/CU = 16 waves/CU.
__global__ __launch_bounds__(512, 4)
void k1_offsets(const float* __restrict__ query, const float* __restrict__ support,
                const int* __restrict__ neighbors, const unsigned int* __restrict__ fp1,
                const float* __restrict__ kpoints,
                const unsigned short* __restrict__ dwB_hi,
                const unsigned short* __restrict__ dwB_lo,
                const float* __restrict__ bias, float* __restrict__ defkp)
{
    __shared__ unsigned short wfA_hi[8 * WST];          // 32768 B
    __shared__ unsigned short wfA_lo[8 * WST];          // 32768 B
    __shared__ float relx[256], rely[256], relz[256];   // 3072 B
    __shared__ int   nbr_s[256];                        // 1024 B
    __shared__ float kp_s[48];                          // 192 B
    __shared__ f32x4 cred[3 * 64];                      // 3072 B

    const int t = threadIdx.x;
    const int qbase = blockIdx.x * 8;
    if (t < 45) kp_s[t] = kpoints[t];
    if (t >= 45 && t < 48) kp_s[t] = 0.f;

    if (t < 256) {
        const int e = t >> 5, n = t & 31;
        const int q = qbase + e;
        const int idx = neighbors[q * NN + n];
        nbr_s[t] = idx;
        relx[t] = support[idx * 3 + 0] - query[q * 3 + 0];
        rely[t] = support[idx * 3 + 1] - query[q * 3 + 1];
        relz[t] = support[idx * 3 + 2] - query[q * 3 + 2];
    }
    __syncthreads();

    const int wave = t >> 6, lane = t & 63;
    const int quad = lane >> 4, low = lane & 15;

    // Phase B: wf0[ee][kf] = sum_n w0 * feat  (split-bf16, fp32 C); ee = wave
    {
        const int ee = wave;
        const int kb = (low < KPN) ? low * 3 : 0;
        const float kx = kp_s[kb + 0], ky = kp_s[kb + 1], kz = kp_s[kb + 2];
        union { unsigned short u[8]; bf16x8 v; } ah, al;
        int rows[8];
        #pragma unroll
        for (int j = 0; j < 8; j++) {
            const int ni = ee * 32 + quad * 8 + j;
            rows[j] = nbr_s[ni];
            const float dx = relx[ni] - kx;
            const float dy = rely[ni] - ky;
            const float dz = relz[ni] - kz;
            const float d = sqrtf(dx * dx + dy * dy + dz * dz);
            float w = 1.0f - d * INV_EXT;
            w = (low < KPN && w > 0.f) ? w : 0.f;
            const unsigned short h = f2bf(w);
            ah.u[j] = h;
            al.u[j] = f2bf(w - bf2f(h));
        }
        #pragma unroll
        for (int fp = 0; fp < 4; fp++) {
            union { unsigned int u[4]; bf16x8 v; } bhA, blA, bhB, blB;
            #pragma unroll
            for (int jj = 0; jj < 4; jj++) {
                const uint2 d0 = *(const uint2*)&fp1[rows[2 * jj] * 128 + fp * 32 + low * 2];
                const uint2 d1 = *(const uint2*)&fp1[rows[2 * jj + 1] * 128 + fp * 32 + low * 2];
                bhA.u[jj] = __builtin_amdgcn_perm(d1.x, d0.x, 0x05040100u);
                bhB.u[jj] = __builtin_amdgcn_perm(d1.x, d0.x, 0x07060302u);
                blA.u[jj] = __builtin_amdgcn_perm(d1.y, d0.y, 0x05040100u);
                blB.u[jj] = __builtin_amdgcn_perm(d1.y, d0.y, 0x07060302u);
            }
            #pragma unroll
            for (int hh2 = 0; hh2 < 2; hh2++) {
                const bf16x8 bh = hh2 ? bhB.v : bhA.v;
                const bf16x8 bl = hh2 ? blB.v : blA.v;
                const int ft = fp * 2 + hh2;
                f32x4 acc = {0.f, 0.f, 0.f, 0.f};
                acc = __builtin_amdgcn_mfma_f32_16x16x32_bf16(al.v, bh, acc, 0, 0, 0);
                acc = __builtin_amdgcn_mfma_f32_16x16x32_bf16(ah.v, bl, acc, 0, 0, 0);
                acc = __builtin_amdgcn_mfma_f32_16x16x32_bf16(ah.v, bh, acc, 0, 0, 0);
                const int col  = ft * 16 + low;
                const int base = ee * WST + SWZ(ee, col >> 1) + ((col & 1) << 4) + quad * 4;
                const unsigned short h0 = f2bf(acc[0]), h1 = f2bf(acc[1]);
                const unsigned short h2 = f2bf(acc[2]), h3 = f2bf(acc[3]);
                unsigned int* ph = (unsigned int*)&wfA_hi[base];
                ph[0] = (unsigned int)h0 | ((unsigned int)h1 << 16);
                ph[1] = (unsigned int)h2 | ((unsigned int)h3 << 16);
                unsigned int* pl = (unsigned int*)&wfA_lo[base];
                pl[0] = (unsigned int)f2bf(acc[0] - bf2f(h0)) |
                        ((unsigned int)f2bf(acc[1] - bf2f(h1)) << 16);
                pl[1] = (unsigned int)f2bf(acc[2] - bf2f(h2)) |
                        ((unsigned int)f2bf(acc[3] - bf2f(h3)) << 16);
            }
        }
    }
    __syncthreads();

    // Phase C: feat0[8e x 48o] = wf0[8e x 2048] * dwB[2048 x 48]  (split-bf16)
    // 6 waves: nt = wave>>1, half = wave&1 (32 kt each); reduce via cred.
    f32x4 acc = {0.f, 0.f, 0.f, 0.f};
    const int nt = wave >> 1, half = wave & 1;
    if (wave < 6) {
        const bf16x8* Bh = (const bf16x8*)dwB_hi;
        const bf16x8* Bl = (const bf16x8*)dwB_lo;
        const int rl = low & 7;            // A row (rows 8..15 duplicate 0..7)
        const int arow = rl * WST;
        const int kt0 = half * 32;
        #pragma unroll 2
        for (int kt = kt0; kt < kt0 + 32; kt++) {
            const int ao = arow + SWZ(rl, kt) + quad * 8;
            bf16x8 a_h = *(const bf16x8*)&wfA_hi[ao];
            bf16x8 a_l = *(const bf16x8*)&wfA_lo[ao];
            bf16x8 b_h = Bh[(nt * KT2 + kt) * 64 + lane];
            bf16x8 b_l = Bl[(nt * KT2 + kt) * 64 + lane];
            acc = __builtin_amdgcn_mfma_f32_16x16x32_bf16(a_l, b_h, acc, 0, 0, 0);
            acc = __builtin_amdgcn_mfma_f32_16x16x32_bf16(a_h, b_l, acc, 0, 0, 0);
            acc = __builtin_amdgcn_mfma_f32_16x16x32_bf16(a_h, b_h, acc, 0, 0, 0);
        }
        if (half == 1) cred[nt * 64 + lane] = acc;
    } else if (wave == 6 && lane < 24) {
        defkp[(qbase + lane / 3) * 45 + (lane % 3)] = kp_s[lane % 3];
    }
    __syncthreads();

    if (wave < 6 && half == 0) {
        f32x4 o2 = cred[nt * 64 + lane];
        acc[0] += o2[0]; acc[1] += o2[1]; acc[2] += o2[2]; acc[3] += o2[3];
        const int o = nt * 16 + low;
        if (quad < 2 && o < OD) {
            const float bo = bias[o] + kp_s[3 + o];
            #pragma unroll
            for (int r = 0; r < 4; r++) {
                const int ee = quad * 4 + r;                 // C row = e
                defkp[(qbase + ee) * 45 + 3 + o] = bo + acc[r];
            }
        }
    }
}

// ------------------------- stage 2 (bf16 MFMA): deformable conv -------------------------
// E=16 queries, 512 threads. LDS ~77 KB -> 2 blocks/CU (16 waves).
__global__ __launch_bounds__(512, 4)
void k2_deform(const float* __restrict__ query, const float* __restrict__ support,
               const int* __restrict__ neighbors, const unsigned int* __restrict__ fp2,
               const unsigned short* __restrict__ Bsw, const float* __restrict__ defkp,
               float* __restrict__ out)
{
    __shared__ unsigned short wfA[16 * WST];             // 65536 B
    __shared__ float relx[512], rely[512], relz[512];    // 6144 B
    __shared__ float dk_s[16 * 45];                      // 2880 B
    __shared__ int   nbr_s[512];                         // 2048 B

    const int t = threadIdx.x;
    const int qbase = blockIdx.x * 16;

    for (int i = t; i < 16 * 45; i += 512) dk_s[i] = defkp[qbase * 45 + i];

    const int e = t >> 5, n = t & 31;
    const int q = qbase + e;
    const int idx = neighbors[q * NN + n];
    nbr_s[t] = idx;
    relx[t] = support[idx * 3 + 0] - query[q * 3 + 0];
    rely[t] = support[idx * 3 + 1] - query[q * 3 + 1];
    relz[t] = support[idx * 3 + 2] - query[q * 3 + 2];
    __syncthreads();

    const int wave = t >> 6, lane = t & 63;
    const int quad = lane >> 4, low = lane & 15;

    // wf1 via MFMA; A-frag (w1^T) recomputed per lane from rel + def_kp
    {
        const int kb = (low < KPN) ? low * 3 : 0;
        for (int ei = 0; ei < 2; ei++) {
            const int ee = wave * 2 + ei;
            const float kx = dk_s[ee * 45 + kb + 0];
            const float ky = dk_s[ee * 45 + kb + 1];
            const float kz = dk_s[ee * 45 + kb + 2];
            union { unsigned short u[8]; bf16x8 v; } a;
            int rows[8];
            #pragma unroll
            for (int j = 0; j < 8; j++) {
                const int ni = ee * 32 + quad * 8 + j;
                rows[j] = nbr_s[ni];
                const float dx = relx[ni] - kx;
                const float dy = rely[ni] - ky;
                const float dz = relz[ni] - kz;
                const float d = sqrtf(dx * dx + dy * dy + dz * dz);
                float w = 1.0f - d * INV_EXT;
                w = (low < KPN && w > 0.f) ? w : 0.f;
                a.u[j] = f2bf(w);
            }
            #pragma unroll
            for (int fp = 0; fp < 4; fp++) {
                union { unsigned int u[4]; bf16x8 v; } bA, bB;
                #pragma unroll
                for (int jj = 0; jj < 4; jj++) {
                    const unsigned int d0 = fp2[rows[2 * jj] * 64 + fp * 16 + low];
                    const unsigned int d1 = fp2[rows[2 * jj + 1] * 64 + fp * 16 + low];
                    bA.u[jj] = __builtin_amdgcn_perm(d1, d0, 0x05040100u);
                    bB.u[jj] = __builtin_amdgcn_perm(d1, d0, 0x07060302u);
                }
                #pragma unroll
                for (int hh2 = 0; hh2 < 2; hh2++) {
                    const bf16x8 b = hh2 ? bB.v : bA.v;
                    const int ft = fp * 2 + hh2;
                    f32x4 acc = {0.f, 0.f, 0.f, 0.f};
                    acc = __builtin_amdgcn_mfma_f32_16x16x32_bf16(a.v, b, acc, 0, 0, 0);
                    const int col  = ft * 16 + low;
                    const int base = ee * WST + SWZ(ee, col >> 1) + ((col & 1) << 4) + quad * 4;
                    unsigned int* wp = (unsigned int*)&wfA[base];
                    wp[0] = (unsigned int)f2bf(acc[0]) | ((unsigned int)f2bf(acc[1]) << 16);
                    wp[1] = (unsigned int)f2bf(acc[2]) | ((unsigned int)f2bf(acc[3]) << 16);
                }
            }
        }
    }
    __syncthreads();

    // GEMM2: out[16 x 256] = wf1[16 x 2048] * Bsw[2048 x 256], unroll-batched loads
    {
        const int nt0 = wave * 2, nt1 = nt0 + 1;
        f32x4 acc0 = {0.f, 0.f, 0.f, 0.f}, acc1 = {0.f, 0.f, 0.f, 0.f};
        const bf16x8* Bp = (const bf16x8*)Bsw;
        const int arow = low * WST;
        #pragma unroll 4
        for (int kt = 0; kt < KT2; kt++) {
            bf16x8 a  = *(const bf16x8*)&wfA[arow + SWZ(low, kt) + quad * 8];
            bf16x8 b0 = Bp[(nt0 * KT2 + kt) * 64 + lane];
            bf16x8 b1 = Bp[(nt1 * KT2 + kt) * 64 + lane];
            acc0 = __builtin_amdgcn_mfma_f32_16x16x32_bf16(a, b0, acc0, 0, 0, 0);
            acc1 = __builtin_amdgcn_mfma_f32_16x16x32_bf16(a, b1, acc1, 0, 0, 0);
        }
        #pragma unroll
        for (int r = 0; r < 4; r++) {
            const int ee = quad * 4 + r;
            out[(qbase + ee) * FO + nt0 * 16 + low] = acc0[r];
            out[(qbase + ee) * FO + nt1 * 16 + low] = acc1[r];
        }
    }
}

// -------------------------------------------------------------------------
extern "C" void kernel_launch(void* const* d_in, const int* in_sizes, int n_in,
                              void* d_out, int out_size, void* d_ws, size_t ws_size,
                              hipStream_t stream) {
    const float* query     = (const float*)d_in[0];
    const float* support   = (const float*)d_in[1];
    const int*   neighbors = (const int*)  d_in[2];
    const float* features  = (const float*)d_in[3];
    const float* kpoints   = (const float*)d_in[4];
    const float* weight    = (const float*)d_in[5];
    const float* dweight   = (const float*)d_in[6];
    const float* bias      = (const float*)d_in[7];
    float*       out       = (float*)d_out;

    char* ws = (char*)d_ws;
    unsigned int*   fp1  = (unsigned int*)(ws + WS_FP1);
    unsigned int*   fp2  = (unsigned int*)(ws + WS_FP2);
    unsigned short* Bsw  = (unsigned short*)(ws + WS_BSW);
    unsigned short* dwBh = (unsigned short*)(ws + WS_DWBH);
    unsigned short* dwBl = (unsigned short*)(ws + WS_DWBL);
    float*          defkp = (float*)(ws + WS_DEFKP);

    pre_all<<<4400, 256, 0, stream>>>(features, fp1, fp2, weight, Bsw,
                                      dweight, dwBh, dwBl);
    k1_offsets<<<NQ / 8, 512, 0, stream>>>(query, support, neighbors, fp1,
                                           kpoints, dwBh, dwBl, bias, defkp);
    k2_deform<<<NQ / 16, 512, 0, stream>>>(query, support, neighbors, fp2,
                                           Bsw, defkp, out);
}